// Round 3
// baseline (236.090 us; speedup 1.0000x reference)
//
#include <hip/hip_runtime.h>
#include <hip/hip_bf16.h>

// SNN IF scan, T=4. Memory-bound: 134 MB in + 134 MB out, ~3 flops/elem.
// R1/R2 change vs R0: (1) issue ALL 8 loads (2 cols x 4 timesteps) before any
// compute -> 8 outstanding vmem ops/thread instead of 1 (R0 had VGPR=16,
// i.e. serialized load->use->store per timestep, 3.27 TB/s effective).
// (2) non-temporal stores: output never re-read; keep LLC holding x.
// R2 fix: __builtin_nontemporal_store needs a NATIVE vector type, not HIP's
// float4 class -> use ext_vector_type(4).

#define T_STEPS 4

typedef float vfloat4 __attribute__((ext_vector_type(4)));

__global__ __launch_bounds__(256) void IF_18622978195596_kernel(
    const vfloat4* __restrict__ x, const float* __restrict__ thresh_p,
    vfloat4* __restrict__ out, int n4) {
    const int i0 = blockIdx.x * (256 * 2) + threadIdx.x;
    const int i1 = i0 + 256;
    const float th = *thresh_p;

    const bool v0 = i0 < n4;
    const bool v1 = i1 < n4;

    // ---- load phase: up to 8 independent loads in flight ----
    vfloat4 xv[T_STEPS][2];
#pragma unroll
    for (int t = 0; t < T_STEPS; ++t) {
        const size_t base = (size_t)t * n4;
        if (v0) xv[t][0] = x[base + i0];
        if (v1) xv[t][1] = x[base + i1];
    }

    // ---- compute + store phase ----
#pragma unroll
    for (int c = 0; c < 2; ++c) {
        const bool v = c ? v1 : v0;
        if (!v) continue;
        const int i = c ? i1 : i0;
        vfloat4 mem = {0.5f * th, 0.5f * th, 0.5f * th, 0.5f * th};
#pragma unroll
        for (int t = 0; t < T_STEPS; ++t) {
            mem += xv[t][c];
            vfloat4 s;
            s.x = (mem.x >= th) ? th : 0.0f;
            s.y = (mem.y >= th) ? th : 0.0f;
            s.z = (mem.z >= th) ? th : 0.0f;
            s.w = (mem.w >= th) ? th : 0.0f;
            mem -= s;
            __builtin_nontemporal_store(s, &out[(size_t)t * n4 + i]);
        }
    }
}

extern "C" void kernel_launch(void* const* d_in, const int* in_sizes, int n_in,
                              void* d_out, int out_size, void* d_ws, size_t ws_size,
                              hipStream_t stream) {
    const float* x = (const float*)d_in[0];
    const float* thresh = (const float*)d_in[1];
    float* out = (float*)d_out;

    int total = in_sizes[0];              // 33,554,432 floats
    int n_per_t = total / T_STEPS;        // 8,388,608 neurons
    int n4 = n_per_t / 4;                 // 2,097,152 vfloat4 per timestep

    int block = 256;
    int per_block = block * 2;            // 2 vfloat4 per thread
    int grid = (n4 + per_block - 1) / per_block;  // 4096 blocks
    IF_18622978195596_kernel<<<grid, block, 0, stream>>>(
        (const vfloat4*)x, thresh, (vfloat4*)out, n4);
}

// Round 4
// 224.177 us; speedup vs baseline: 1.0531x; 1.0531x over previous
//
#include <hip/hip_runtime.h>
#include <hip/hip_bf16.h>

// SNN IF scan, T=4. Memory-bound: 134 MB in + 134 MB out (~43 us floor at
// 6.3 TB/s). R0/R2 both ran 82 us (~3.3 TB/s combined); R2's batching was
// silently collapsed by the compiler (VGPR=24 can't hold 8 float4s).
// R3: force real MLP — 4 groups/thread x 4 timesteps = 16 independent loads,
// hard-separated from the consume phase by sched_barrier(0) so the scheduler
// can't re-serialize. nt on loads AND stores (single-touch streams, don't
// allocate: all 8 streams are 2^25 B apart -> same L2 set phase).
// VGPR_Count >= ~80 is the check that the batching actually survived.

#define T_STEPS 4
#define UNROLL 4

typedef float vfloat4 __attribute__((ext_vector_type(4)));

__global__ __launch_bounds__(256) void IF_18622978195596_kernel(
    const vfloat4* __restrict__ x, const float* __restrict__ thresh_p,
    vfloat4* __restrict__ out, int n4) {
    // n4 is divisible by 256*UNROLL for this problem (2^21 / 1024 = 2048);
    // host asserts via grid sizing. No per-access guards.
    const int base = blockIdx.x * (256 * UNROLL) + threadIdx.x;
    const float th = *thresh_p;

    // ---- load phase: 16 independent nt loads, all in flight ----
    vfloat4 xv[T_STEPS][UNROLL];
#pragma unroll
    for (int t = 0; t < T_STEPS; ++t) {
#pragma unroll
        for (int u = 0; u < UNROLL; ++u) {
            xv[t][u] = __builtin_nontemporal_load(
                &x[(size_t)t * n4 + base + u * 256]);
        }
    }
    // nothing may be scheduled across this point
    __builtin_amdgcn_sched_barrier(0);

    // ---- compute + store phase ----
#pragma unroll
    for (int u = 0; u < UNROLL; ++u) {
        const int i = base + u * 256;
        vfloat4 mem = {0.5f * th, 0.5f * th, 0.5f * th, 0.5f * th};
#pragma unroll
        for (int t = 0; t < T_STEPS; ++t) {
            mem += xv[t][u];
            vfloat4 s;
            s.x = (mem.x >= th) ? th : 0.0f;
            s.y = (mem.y >= th) ? th : 0.0f;
            s.z = (mem.z >= th) ? th : 0.0f;
            s.w = (mem.w >= th) ? th : 0.0f;
            mem -= s;
            __builtin_nontemporal_store(s, &out[(size_t)t * n4 + i]);
        }
    }
}

extern "C" void kernel_launch(void* const* d_in, const int* in_sizes, int n_in,
                              void* d_out, int out_size, void* d_ws, size_t ws_size,
                              hipStream_t stream) {
    const float* x = (const float*)d_in[0];
    const float* thresh = (const float*)d_in[1];
    float* out = (float*)d_out;

    int total = in_sizes[0];              // 33,554,432 floats
    int n_per_t = total / T_STEPS;        // 8,388,608 neurons
    int n4 = n_per_t / 4;                 // 2,097,152 vfloat4 per timestep

    int block = 256;
    int per_block = block * UNROLL;       // 1024 vfloat4 per block per t
    int grid = n4 / per_block;            // 2048 blocks (exact for this size)
    IF_18622978195596_kernel<<<grid, block, 0, stream>>>(
        (const vfloat4*)x, thresh, (vfloat4*)out, n4);
}